// Round 4
// baseline (3816.232 us; speedup 1.0000x reference)
//
#include <hip/hip_runtime.h>
#include <hip/hip_bf16.h>
#include <math.h>

#define BB 8
#define NN 1000
#define EE 16000
#define ETOT 17000   // E + N self loops
#define TPRED 12
#define FEAT 13
#define INDIM 14
#define HEADS 8
#define HG 256
#define C1 2048      // HEADS*HG
#define GO 13
#define HID 64

typedef unsigned int  uint32;
typedef unsigned short ushort16;
typedef uint32 uvec4 __attribute__((ext_vector_type(4)));

__device__ __forceinline__ float lrelu(float v){ return v > 0.f ? v : 0.2f*v; }

__device__ __forceinline__ ushort16 f2bf(float f){
    union { float f; uint32 u; } v; v.f = f;
    uint32 r = v.u + 0x7FFFu + ((v.u >> 16) & 1u);   // RNE
    return (ushort16)(r >> 16);
}
__device__ __forceinline__ uint32 pack2(float lo, float hi){
    return (uint32)f2bf(lo) | ((uint32)f2bf(hi) << 16);
}
__device__ __forceinline__ void cvt2(uint32 u, float& lo, float& hi){
    union { uint32 u; float f; } a, b;
    a.u = u << 16; b.u = u & 0xFFFF0000u;
    lo = a.f; hi = b.f;
}

// ---------------- setup kernels (once per launch) ----------------

__global__ void k_init(const float* pm25, float* hn, float* xn, int* count){
    int i = blockIdx.x*blockDim.x + threadIdx.x;
    if (i < BB*NN*HID) hn[i] = 0.f;
    if (i < BB*NN){
        int b = i/NN, n = i%NN;
        xn[i] = pm25[(b*8 + 7)*NN + n];   // pm25_hist[b, -1, n, 0]
    }
    if (i < NN) count[i] = 0;
}

// Wsrc[k][h] = sum_d W1[k, h*256+d] * a_src[h,d]   (and Wdst)
__global__ void k_att1pre(const float* W1, const float* asrc, const float* adst,
                          float* Wsrc, float* Wdst){
    int k = blockIdx.x >> 3, h = blockIdx.x & 7;
    int tid = threadIdx.x;                 // 256 threads = 256 dims
    float wv = W1[k*C1 + h*HG + tid];
    float ps = wv * asrc[h*HG + tid];
    float pd = wv * adst[h*HG + tid];
    #pragma unroll
    for (int m=1;m<64;m<<=1){ ps += __shfl_xor(ps,m); pd += __shfl_xor(pd,m); }
    __shared__ float rs[4], rd[4];
    int w = tid>>6;
    if ((tid&63)==0){ rs[w]=ps; rd[w]=pd; }
    __syncthreads();
    if (tid==0){
        Wsrc[k*8+h] = rs[0]+rs[1]+rs[2]+rs[3];
        Wdst[k*8+h] = rd[0]+rd[1]+rd[2]+rd[3];
    }
}

// pack W1 to bf16 pairs: w1pk[k*1024 + c2] = (W1[k][2c2], W1[k][2c2+1])
__global__ void k_packW1(const float* W1, uint32* w1pk){
    int i = blockIdx.x*blockDim.x + threadIdx.x;
    if (i < 14*1024){
        int k = i >> 10, c2 = i & 1023;
        w1pk[i] = pack2(W1[k*C1 + 2*c2], W1[k*C1 + 2*c2 + 1]);
    }
}

// build 16-col matrix per channel c: [W2[c][0..12], w2s[c], w2d[c], 0] packed bf16
// layout w2pk[p*2048 + c] = pair (col 2p, col 2p+1)
__global__ void k_att2pre(const float* W2, const float* a2s, const float* a2d,
                          uint32* w2pk){
    int c = blockIdx.x*blockDim.x + threadIdx.x;
    if (c < C1){
        float col[16];
        float ss=0.f, dd=0.f;
        #pragma unroll
        for (int j=0;j<GO;j++){ float w=W2[c*GO+j]; col[j]=w; ss+=w*a2s[j]; dd+=w*a2d[j]; }
        col[13]=ss; col[14]=dd; col[15]=0.f;
        #pragma unroll
        for (int p=0;p<8;p++) w2pk[p*2048 + c] = pack2(col[2*p], col[2*p+1]);
    }
}

__global__ void k_count(const int* ei, int* count){
    int e = blockIdx.x*blockDim.x + threadIdx.x;
    if (e < ETOT){
        int dst = (e<EE) ? ei[EE+e] : (e-EE);
        atomicAdd(&count[dst], 1);
    }
}

__global__ void k_scan(const int* count, int* offs, int* cursor){
    __shared__ int s[1024];
    int tid = threadIdx.x;
    int myc = (tid<NN) ? count[tid] : 0;
    s[tid] = myc;
    __syncthreads();
    for (int d=1; d<1024; d<<=1){
        int v = (tid>=d) ? s[tid-d] : 0;
        __syncthreads();
        s[tid] += v;
        __syncthreads();
    }
    if (tid<NN){
        int off = s[tid] - myc;   // exclusive
        offs[tid] = off; cursor[tid] = off;
    }
    if (tid==NN-1) offs[NN] = s[tid];
}

__global__ void k_fill(const int* ei, int* cursor, int* csr_src){
    int e = blockIdx.x*blockDim.x + threadIdx.x;
    if (e < ETOT){
        int src = (e<EE) ? ei[e]    : (e-EE);
        int dst = (e<EE) ? ei[EE+e] : (e-EE);
        int pos = atomicAdd(&cursor[dst], 1);
        csr_src[pos] = src;
    }
}

// ---------------- per-step kernels ----------------

// per (b,n): scores ssrc[8], sdst[8] = x @ Wsrc/Wdst (x = [xn, feat_t], 14-wide)
// and pack x into bf16 pairs xpk[bn*8 + p] (7 pairs + zero pad)
__global__ __launch_bounds__(256) void k_score(int t, const float* feat, const float* xn,
        const float* Wsrc, const float* Wdst, float* ssrc, float* sdst, uint32* xpk){
    int bn = blockIdx.x*256 + threadIdx.x;
    if (bn >= BB*NN) return;
    int b = bn/NN, n = bn%NN;
    float x[INDIM];
    x[0] = xn[bn];
    const float* fp = feat + ((size_t)(b*20 + 8 + t)*NN + n)*FEAT;
    #pragma unroll
    for (int k=0;k<FEAT;k++) x[k+1] = fp[k];
    #pragma unroll
    for (int h=0;h<8;h++){
        float ss=0.f, dd=0.f;
        #pragma unroll
        for (int k=0;k<INDIM;k++){ ss += x[k]*Wsrc[k*8+h]; dd += x[k]*Wdst[k*8+h]; }
        ssrc[bn*8+h] = ss; sdst[bn*8+h] = dd;
    }
    #pragma unroll
    for (int p=0;p<7;p++) xpk[bn*8+p] = pack2(x[2*p], x[2*p+1]);
    xpk[bn*8+7] = 0u;
}

// per (b,dst), 1 wave: 8-head softmax over incoming edges, aggregate 14-dim x:
// agg[bn*128 + h*16 + k] = sum_src alpha_h * x[src][k]
__global__ __launch_bounds__(64) void k_agg14(const uint32* xpk, const float* ssrc,
        const float* sdst, const int* offs, const int* csr, float* agg){
    int lane = threadIdx.x;
    int blk = blockIdx.x;
    int b = blk & 7, dstn = blk >> 3;
    int bn = b*NN + dstn;
    int base = offs[dstn], deg = offs[dstn+1]-base;
    int h = lane & 7, slot = lane >> 3;
    float sdd = sdst[bn*8 + h];
    // pass 1: per-head max
    float mloc = -1e30f;
    for (int i=slot;i<deg;i+=8){
        int s = csr[base+i];
        mloc = fmaxf(mloc, lrelu(ssrc[(b*NN+s)*8+h]+sdd));
    }
    mloc = fmaxf(mloc, __shfl_xor(mloc,8));
    mloc = fmaxf(mloc, __shfl_xor(mloc,16));
    mloc = fmaxf(mloc, __shfl_xor(mloc,32));
    // pass 2: per-head denom
    float dloc = 0.f;
    for (int i=slot;i<deg;i+=8){
        int s = csr[base+i];
        dloc += __expf(lrelu(ssrc[(b*NN+s)*8+h]+sdd)-mloc);
    }
    dloc += __shfl_xor(dloc,8); dloc += __shfl_xor(dloc,16); dloc += __shfl_xor(dloc,32);
    float rden = 1.f/dloc;
    // pass 3 remap: lane = h2*8 + kk, kk owns channels 2kk,2kk+1
    int kk = lane & 7, h2 = lane >> 3;
    float m2   = __shfl(mloc, h2);
    float r2   = __shfl(rden, h2);
    float sdd2 = __shfl(sdd,  h2);
    float a0=0.f, a1=0.f;
    for (int e=0;e<deg;e++){
        int s = csr[base+e];
        float sc = lrelu(ssrc[(b*NN+s)*8+h2] + sdd2);
        float al = __expf(sc - m2)*r2;
        float x0,x1; cvt2(xpk[(b*NN+s)*8+kk], x0, x1);
        a0 += al*x0; a1 += al*x1;
    }
    float2 st; st.x = a0; st.y = a1;
    *(float2*)(agg + (size_t)bn*128 + h2*16 + 2*kk) = st;
}

// fused expand(14->2048) + bias + elu + contract(2048->15):
// h2[bn][13], s2s[bn], s2d[bn]. Weights register-resident (packed bf16).
// thread t owns channels 8t..8t+7 (head hh = t>>5).
__global__ __launch_bounds__(256,2) void k_expand(const float* agg, const uint32* w1pk,
        const uint32* w2pk, const float* b1, float* h2, float* s2s, float* s2d){
    int tid = threadIdx.x;
    int hh = tid >> 5;
    uint32 w1r[56];
    #pragma unroll
    for (int k=0;k<14;k++){
        uvec4 u = *(const uvec4*)(w1pk + k*1024 + 4*tid);
        w1r[4*k+0]=u.x; w1r[4*k+1]=u.y; w1r[4*k+2]=u.z; w1r[4*k+3]=u.w;
    }
    uint32 w2r[64];
    #pragma unroll
    for (int p=0;p<8;p++){
        uvec4 ua = *(const uvec4*)(w2pk + p*2048 + 8*tid);
        uvec4 ub = *(const uvec4*)(w2pk + p*2048 + 8*tid + 4);
        w2r[8*p+0]=ua.x; w2r[8*p+1]=ua.y; w2r[8*p+2]=ua.z; w2r[8*p+3]=ua.w;
        w2r[8*p+4]=ub.x; w2r[8*p+5]=ub.y; w2r[8*p+6]=ub.z; w2r[8*p+7]=ub.w;
    }
    float b1r[8];
    #pragma unroll
    for (int j=0;j<8;j++) b1r[j] = b1[8*tid+j];
    __shared__ float sred[256*20];
    __shared__ float red2[64];
    for (int idx = blockIdx.x; idx < BB*NN; idx += gridDim.x){
        float ag[14];
        {
            const float4* ap = (const float4*)(agg + (size_t)idx*128 + hh*16);
            float4 A0=ap[0], A1=ap[1], A2=ap[2], A3=ap[3];
            ag[0]=A0.x; ag[1]=A0.y; ag[2]=A0.z; ag[3]=A0.w;
            ag[4]=A1.x; ag[5]=A1.y; ag[6]=A1.z; ag[7]=A1.w;
            ag[8]=A2.x; ag[9]=A2.y; ag[10]=A2.z; ag[11]=A2.w;
            ag[12]=A3.x; ag[13]=A3.y;
        }
        float v[8];
        #pragma unroll
        for (int j=0;j<8;j++) v[j] = b1r[j];
        #pragma unroll
        for (int k=0;k<14;k++){
            float akv = ag[k];
            #pragma unroll
            for (int q=0;q<4;q++){
                float lo,hi; cvt2(w1r[4*k+q], lo, hi);
                v[2*q]   += akv*lo;
                v[2*q+1] += akv*hi;
            }
        }
        #pragma unroll
        for (int j=0;j<8;j++) v[j] = v[j] > 0.f ? v[j] : __expf(v[j]) - 1.f;
        float acc[16];
        #pragma unroll
        for (int p=0;p<8;p++){
            float s0=0.f, s1=0.f;
            #pragma unroll
            for (int j=0;j<8;j++){
                float lo,hi; cvt2(w2r[8*p+j], lo, hi);
                s0 += v[j]*lo; s1 += v[j]*hi;
            }
            acc[2*p]=s0; acc[2*p+1]=s1;
        }
        #pragma unroll
        for (int q=0;q<4;q++){
            float4 fv; fv.x=acc[4*q]; fv.y=acc[4*q+1]; fv.z=acc[4*q+2]; fv.w=acc[4*q+3];
            *(float4*)(sred + tid*20 + 4*q) = fv;
        }
        __syncthreads();
        int j = tid & 15, g = tid >> 4;
        float s = 0.f;
        #pragma unroll
        for (int i=0;i<16;i++) s += sred[(g + 16*i)*20 + j];
        s += __shfl_xor(s, 16);
        s += __shfl_xor(s, 32);
        int lane = tid & 63, w = tid >> 6;
        if (lane < 16) red2[w*16 + lane] = s;
        __syncthreads();
        if (tid < 15){
            float r = red2[tid] + red2[16+tid] + red2[32+tid] + red2[48+tid];
            if (tid < GO)      h2[idx*GO + tid] = r;
            else if (tid==13)  s2s[idx] = r;
            else               s2d[idx] = r;
        }
        __syncthreads();
    }
}

// per-dst 1-head softmax + aggregation of h2 -> g (+bias2). Edge-parallel.
__global__ __launch_bounds__(64) void k_gat2agg(const float* h2, const float* s2src,
        const float* s2dst, const int* offs, const int* csr_src,
        const float* bias2, float* g){
    int lane = threadIdx.x;
    int blk = blockIdx.x;
    int b = blk & 7, n = blk >> 3;
    int bn = b*NN + n;
    int base = offs[n], deg = offs[n+1]-base;
    float sdd = s2dst[bn];
    float mloc = -1e30f;
    for (int i=lane;i<deg;i+=64){
        int s = csr_src[base+i];
        mloc = fmaxf(mloc, lrelu(s2src[b*NN+s] + sdd));
    }
    #pragma unroll
    for (int m=1;m<64;m<<=1) mloc = fmaxf(mloc, __shfl_xor(mloc,m));
    float dloc = 0.f;
    for (int i=lane;i<deg;i+=64){
        int s = csr_src[base+i];
        dloc += __expf(lrelu(s2src[b*NN+s] + sdd) - mloc);
    }
    #pragma unroll
    for (int m=1;m<64;m<<=1) dloc += __shfl_xor(dloc,m);
    float rd = 1.f / dloc;
    float acc[GO];
    #pragma unroll
    for (int c=0;c<GO;c++) acc[c]=0.f;
    for (int i=lane;i<deg;i+=64){
        int s = csr_src[base+i];
        float al = __expf(lrelu(s2src[b*NN+s] + sdd) - mloc) * rd;
        const float* hr = h2 + (size_t)(b*NN+s)*GO;
        #pragma unroll
        for (int c=0;c<GO;c++) acc[c] += al*hr[c];
    }
    #pragma unroll
    for (int c=0;c<GO;c++){
        #pragma unroll
        for (int m=1;m<64;m<<=1) acc[c] += __shfl_xor(acc[c],m);
    }
    if (lane==0){
        #pragma unroll
        for (int c=0;c<GO;c++) g[bn*GO+c] = acc[c] + bias2[c];
    }
}

// GRU step + fc_out; writes hn, xn, and d_out[b, t, n]
__global__ __launch_bounds__(256) void k_gru(int t, const float* feat, const float* gbuf,
        const float* Wih, const float* Whh, const float* bih, const float* bhh,
        const float* fcw, const float* fcb,
        float* hn, float* xn, float* out){
    __shared__ float sWih[192*27];
    __shared__ float sWhh[192*65];     // row stride 65: bank-conflict-free
    __shared__ float sb[449];          // bih[192], bhh[192], fcw[64], fcb
    __shared__ float gxs[4][28];
    __shared__ float hs[4][64];
    int tid = threadIdx.x;
    for (int i=tid;i<192*27;i+=256) sWih[i] = Wih[i];
    for (int i=tid;i<192*64;i+=256) sWhh[(i>>6)*65 + (i&63)] = Whh[i];
    for (int i=tid;i<192;i+=256){ sb[i] = bih[i]; sb[192+i] = bhh[i]; }
    if (tid<64) sb[384+tid] = fcw[tid];
    if (tid==0) sb[448] = fcb[0];
    __syncthreads();
    int w = tid>>6, lane = tid&63;
    for (int i=0;i<4;i++){
        int bn = blockIdx.x*16 + i*4 + w;
        int b = bn/NN, n = bn%NN;
        if (lane < GO)       gxs[w][lane] = gbuf[bn*GO+lane];
        else if (lane == GO) gxs[w][GO]   = xn[bn];
        else if (lane < 27)  gxs[w][lane] = feat[((size_t)(b*20 + 8 + t)*NN + n)*FEAT + (lane-14)];
        hs[w][lane] = hn[bn*HID + lane];
        __syncthreads();
        float ir = sb[lane], iz = sb[64+lane], inn = sb[128+lane];
        #pragma unroll
        for (int c=0;c<27;c++){
            float xv = gxs[w][c];
            ir  += sWih[lane*27        + c]*xv;
            iz  += sWih[(64+lane)*27   + c]*xv;
            inn += sWih[(128+lane)*27  + c]*xv;
        }
        float hr = sb[192+lane], hz = sb[256+lane], hnv = sb[320+lane];
        #pragma unroll
        for (int j=0;j<64;j++){
            float hv = hs[w][j];
            hr  += sWhh[lane*65        + j]*hv;
            hz  += sWhh[(64+lane)*65   + j]*hv;
            hnv += sWhh[(128+lane)*65  + j]*hv;
        }
        float r  = 1.f/(1.f+__expf(-(ir+hr)));
        float z  = 1.f/(1.f+__expf(-(iz+hz)));
        float nv = tanhf(inn + r*hnv);
        float hold = hs[w][lane];
        float hnew = (1.f - z)*nv + z*hold;
        hn[bn*HID+lane] = hnew;
        float xv = hnew * sb[384+lane];
        #pragma unroll
        for (int m=1;m<64;m<<=1) xv += __shfl_xor(xv,m);
        if (lane==0){
            float res = xv + sb[448];
            xn[bn] = res;
            out[(b*TPRED + t)*NN + n] = res;
        }
        __syncthreads();
    }
}

// ---------------- host ----------------

extern "C" void kernel_launch(void* const* d_in, const int* in_sizes, int n_in,
                              void* d_out, int out_size, void* d_ws, size_t ws_size,
                              hipStream_t stream){
    const float* pm25 = (const float*)d_in[0];
    const float* feat = (const float*)d_in[1];
    const int*   ei   = (const int*)  d_in[2];
    const float* W1   = (const float*)d_in[3];
    const float* a1s  = (const float*)d_in[4];
    const float* a1d  = (const float*)d_in[5];
    const float* b1   = (const float*)d_in[6];
    const float* W2   = (const float*)d_in[7];
    const float* a2s  = (const float*)d_in[8];
    const float* a2d  = (const float*)d_in[9];
    const float* b2   = (const float*)d_in[10];
    const float* Wih  = (const float*)d_in[11];
    const float* Whh  = (const float*)d_in[12];
    const float* bih  = (const float*)d_in[13];
    const float* bhh  = (const float*)d_in[14];
    const float* fcw  = (const float*)d_in[15];
    const float* fcb  = (const float*)d_in[16];
    float* out = (float*)d_out;

    float* f = (float*)d_ws;
    size_t o = 0;
    float* ssrc1 = f+o; o += (size_t)BB*NN*8;
    float* sdst1 = f+o; o += (size_t)BB*NN*8;
    float* agg   = f+o; o += (size_t)BB*NN*128;
    float* h2    = f+o; o += (size_t)BB*NN*GO + 8;
    float* s2s   = f+o; o += (size_t)BB*NN;
    float* s2d   = f+o; o += (size_t)BB*NN;
    float* gb    = f+o; o += (size_t)BB*NN*GO + 8;
    float* hn    = f+o; o += (size_t)BB*NN*HID;
    float* xn    = f+o; o += (size_t)BB*NN;
    float* Wsrc  = f+o; o += INDIM*8;
    float* Wdst  = f+o; o += INDIM*8;
    uint32* xpk  = (uint32*)(f+o); o += (size_t)BB*NN*8;
    uint32* w1pk = (uint32*)(f+o); o += 14*1024;
    uint32* w2pk = (uint32*)(f+o); o += 8*2048;
    int* ibase  = (int*)(f+o);
    int* count  = ibase;
    int* cursor = ibase + NN;
    int* offs   = ibase + 2*NN;
    int* csr    = ibase + 2*NN + NN + 1;

    k_init   <<<2000,256,0,stream>>>(pm25, hn, xn, count);
    k_att1pre<<<112, 256,0,stream>>>(W1, a1s, a1d, Wsrc, Wdst);
    k_packW1 <<<56,  256,0,stream>>>(W1, w1pk);
    k_att2pre<<<8,   256,0,stream>>>(W2, a2s, a2d, w2pk);
    k_count  <<<67,  256,0,stream>>>(ei, count);
    k_scan   <<<1,  1024,0,stream>>>(count, offs, cursor);
    k_fill   <<<67,  256,0,stream>>>(ei, cursor, csr);

    for (int t=0; t<TPRED; t++){
        k_score  <<<32,  256,0,stream>>>(t, feat, xn, Wsrc, Wdst, ssrc1, sdst1, xpk);
        k_agg14  <<<8000, 64,0,stream>>>(xpk, ssrc1, sdst1, offs, csr, agg);
        k_expand <<<512, 256,0,stream>>>(agg, w1pk, w2pk, b1, h2, s2s, s2d);
        k_gat2agg<<<8000, 64,0,stream>>>(h2, s2s, s2d, offs, csr, b2, gb);
        k_gru    <<<500, 256,0,stream>>>(t, feat, gb, Wih, Whh, bih, bhh, fcw, fcb, hn, xn, out);
    }
}

// Round 6
// 987.627 us; speedup vs baseline: 3.8640x; 3.8640x over previous
//
#include <hip/hip_runtime.h>
#include <hip/hip_bf16.h>
#include <math.h>

#define BB 8
#define NN 1000
#define EE 16000
#define ETOT 17000   // E + N self loops
#define TPRED 12
#define FEAT 13
#define INDIM 14
#define HEADS 8
#define HG 256
#define C1 2048      // HEADS*HG
#define GO 13
#define HID 64

typedef unsigned int  uint32;
typedef unsigned short ushort16;
typedef uint32 uvec4 __attribute__((ext_vector_type(4)));
typedef __fp16 hf2 __attribute__((ext_vector_type(2)));

union U32H2 { uint32 u; hf2 h; };
__device__ __forceinline__ hf2 u2h(uint32 u){ U32H2 c; c.u=u; return c.h; }
__device__ __forceinline__ uint32 h2u(hf2 h){ U32H2 c; c.h=h; return c.u; }

#if __has_builtin(__builtin_amdgcn_fdot2)
__device__ __forceinline__ float FDOT2(hf2 a, hf2 b, float c){
    return __builtin_amdgcn_fdot2(a, b, c, false);
}
#else
__device__ __forceinline__ float FDOT2(hf2 a, hf2 b, float c){
    return c + (float)a.x*(float)b.x + (float)a.y*(float)b.y;
}
#endif

__device__ __forceinline__ float lrelu(float v){ return v > 0.f ? v : 0.2f*v; }

__device__ __forceinline__ ushort16 f2bf(float f){
    union { float f; uint32 u; } v; v.f = f;
    uint32 r = v.u + 0x7FFFu + ((v.u >> 16) & 1u);   // RNE
    return (ushort16)(r >> 16);
}
__device__ __forceinline__ uint32 pack2(float lo, float hi){
    return (uint32)f2bf(lo) | ((uint32)f2bf(hi) << 16);
}
__device__ __forceinline__ void cvt2(uint32 u, float& lo, float& hi){
    union { uint32 u; float f; } a, b;
    a.u = u << 16; b.u = u & 0xFFFF0000u;
    lo = a.f; hi = b.f;
}

// ---------------- setup kernels (once per launch) ----------------

__global__ void k_init(const float* pm25, float* hn, float* xn, int* count){
    int i = blockIdx.x*blockDim.x + threadIdx.x;
    if (i < BB*NN*HID) hn[i] = 0.f;
    if (i < BB*NN){
        int b = i/NN, n = i%NN;
        xn[i] = pm25[(b*8 + 7)*NN + n];   // pm25_hist[b, -1, n, 0]
    }
    if (i < NN) count[i] = 0;
}

// Wsrc[k][h] = sum_d W1[k, h*256+d] * a_src[h,d]   (and Wdst)
__global__ void k_att1pre(const float* W1, const float* asrc, const float* adst,
                          float* Wsrc, float* Wdst){
    int k = blockIdx.x >> 3, h = blockIdx.x & 7;
    int tid = threadIdx.x;                 // 256 threads = 256 dims
    float wv = W1[k*C1 + h*HG + tid];
    float ps = wv * asrc[h*HG + tid];
    float pd = wv * adst[h*HG + tid];
    #pragma unroll
    for (int m=1;m<64;m<<=1){ ps += __shfl_xor(ps,m); pd += __shfl_xor(pd,m); }
    __shared__ float rs[4], rd[4];
    int w = tid>>6;
    if ((tid&63)==0){ rs[w]=ps; rd[w]=pd; }
    __syncthreads();
    if (tid==0){
        Wsrc[k*8+h] = rs[0]+rs[1]+rs[2]+rs[3];
        Wdst[k*8+h] = rd[0]+rd[1]+rd[2]+rd[3];
    }
}

// pack W1 to f16 k-pairs: w1pk[c*8 + kk] = (W1[2kk][c], W1[2kk+1][c]), kk<7; slot 7 = 0
__global__ void k_packW1(const float* W1, uint32* w1pk){
    int i = blockIdx.x*blockDim.x + threadIdx.x;
    if (i < C1*8){
        int c = i >> 3, kk = i & 7;
        float lo = (kk < 7) ? W1[(2*kk)*C1 + c]   : 0.f;
        float hi = (kk < 7) ? W1[(2*kk+1)*C1 + c] : 0.f;
        w1pk[i] = h2u(__builtin_amdgcn_cvt_pkrtz(lo, hi));
    }
}

// per channel-PAIR m: 16-col matrix rows for channels 2m,2m+1:
// col j<13 = W2[c][j]; col13 = W2[c]@a2s; col14 = W2[c]@a2d; col15 = 0
// w2pk[m*16 + j] = f16pair( colA[j], colB[j] )
__global__ void k_att2pre(const float* W2, const float* a2s, const float* a2d,
                          uint32* w2pk){
    int m = blockIdx.x*blockDim.x + threadIdx.x;
    if (m < C1/2){
        int c0 = 2*m, c1 = 2*m+1;
        float colA[16], colB[16];
        float ssA=0.f, ddA=0.f, ssB=0.f, ddB=0.f;
        #pragma unroll
        for (int j=0;j<GO;j++){
            float wA = W2[c0*GO+j], wB = W2[c1*GO+j];
            colA[j]=wA; colB[j]=wB;
            ssA += wA*a2s[j]; ddA += wA*a2d[j];
            ssB += wB*a2s[j]; ddB += wB*a2d[j];
        }
        colA[13]=ssA; colA[14]=ddA; colA[15]=0.f;
        colB[13]=ssB; colB[14]=ddB; colB[15]=0.f;
        #pragma unroll
        for (int j=0;j<16;j++)
            w2pk[m*16+j] = h2u(__builtin_amdgcn_cvt_pkrtz(colA[j], colB[j]));
    }
}

__global__ void k_count(const int* ei, int* count){
    int e = blockIdx.x*blockDim.x + threadIdx.x;
    if (e < ETOT){
        int dst = (e<EE) ? ei[EE+e] : (e-EE);
        atomicAdd(&count[dst], 1);
    }
}

__global__ void k_scan(const int* count, int* offs, int* cursor){
    __shared__ int s[1024];
    int tid = threadIdx.x;
    int myc = (tid<NN) ? count[tid] : 0;
    s[tid] = myc;
    __syncthreads();
    for (int d=1; d<1024; d<<=1){
        int v = (tid>=d) ? s[tid-d] : 0;
        __syncthreads();
        s[tid] += v;
        __syncthreads();
    }
    if (tid<NN){
        int off = s[tid] - myc;   // exclusive
        offs[tid] = off; cursor[tid] = off;
    }
    if (tid==NN-1) offs[NN] = s[tid];
}

__global__ void k_fill(const int* ei, int* cursor, int* csr_src){
    int e = blockIdx.x*blockDim.x + threadIdx.x;
    if (e < ETOT){
        int src = (e<EE) ? ei[e]    : (e-EE);
        int dst = (e<EE) ? ei[EE+e] : (e-EE);
        int pos = atomicAdd(&cursor[dst], 1);
        csr_src[pos] = src;
    }
}

// ---------------- per-step kernels ----------------

// per (b,n): scores ssrc[8], sdst[8] = x @ Wsrc/Wdst (x = [xn, feat_t], 14-wide)
// and pack x into bf16 pairs xpk[bn*8 + p] (7 pairs + zero pad)
__global__ __launch_bounds__(256) void k_score(int t, const float* feat, const float* xn,
        const float* Wsrc, const float* Wdst, float* ssrc, float* sdst, uint32* xpk){
    int bn = blockIdx.x*256 + threadIdx.x;
    if (bn >= BB*NN) return;
    int b = bn/NN, n = bn%NN;
    float x[INDIM];
    x[0] = xn[bn];
    const float* fp = feat + ((size_t)(b*20 + 8 + t)*NN + n)*FEAT;
    #pragma unroll
    for (int k=0;k<FEAT;k++) x[k+1] = fp[k];
    #pragma unroll
    for (int h=0;h<8;h++){
        float ss=0.f, dd=0.f;
        #pragma unroll
        for (int k=0;k<INDIM;k++){ ss += x[k]*Wsrc[k*8+h]; dd += x[k]*Wdst[k*8+h]; }
        ssrc[bn*8+h] = ss; sdst[bn*8+h] = dd;
    }
    #pragma unroll
    for (int p=0;p<7;p++) xpk[bn*8+p] = pack2(x[2*p], x[2*p+1]);
    xpk[bn*8+7] = 0u;
}

// per (b,dst), 1 wave: 8-head softmax over incoming edges, aggregate 14-dim x:
// agg[bn*128 + h*16 + k] = sum_src alpha_h * x[src][k]
__global__ __launch_bounds__(64) void k_agg14(const uint32* xpk, const float* ssrc,
        const float* sdst, const int* offs, const int* csr, float* agg){
    int lane = threadIdx.x;
    int blk = blockIdx.x;
    int b = blk & 7, dstn = blk >> 3;
    int bn = b*NN + dstn;
    int base = offs[dstn], deg = offs[dstn+1]-base;
    int h = lane & 7, slot = lane >> 3;
    float sdd = sdst[bn*8 + h];
    // pass 1: per-head max
    float mloc = -1e30f;
    for (int i=slot;i<deg;i+=8){
        int s = csr[base+i];
        mloc = fmaxf(mloc, lrelu(ssrc[(b*NN+s)*8+h]+sdd));
    }
    mloc = fmaxf(mloc, __shfl_xor(mloc,8));
    mloc = fmaxf(mloc, __shfl_xor(mloc,16));
    mloc = fmaxf(mloc, __shfl_xor(mloc,32));
    // pass 2: per-head denom
    float dloc = 0.f;
    for (int i=slot;i<deg;i+=8){
        int s = csr[base+i];
        dloc += __expf(lrelu(ssrc[(b*NN+s)*8+h]+sdd)-mloc);
    }
    dloc += __shfl_xor(dloc,8); dloc += __shfl_xor(dloc,16); dloc += __shfl_xor(dloc,32);
    float rden = 1.f/dloc;
    // pass 3 remap: lane = h2*8 + kk, kk owns channels 2kk,2kk+1
    int kk = lane & 7, h2 = lane >> 3;
    float m2   = __shfl(mloc, h2);
    float r2   = __shfl(rden, h2);
    float sdd2 = __shfl(sdd,  h2);
    float a0=0.f, a1=0.f;
    for (int e=0;e<deg;e++){
        int s = csr[base+e];
        float sc = lrelu(ssrc[(b*NN+s)*8+h2] + sdd2);
        float al = __expf(sc - m2)*r2;
        float x0,x1; cvt2(xpk[(b*NN+s)*8+kk], x0, x1);
        a0 += al*x0; a1 += al*x1;
    }
    float2 st; st.x = a0; st.y = a1;
    *(float2*)(agg + (size_t)bn*128 + h2*16 + 2*kk) = st;
}

// fused expand(14->2048) + bias + elu + contract(2048->16):
// h2[bn][13], s2s[bn], s2d[bn]. Weights register-resident (packed f16 pairs),
// all math via v_dot2_f32_f16. Thread t owns channels 8t..8t+7 (head hh=t>>5).
__global__ __launch_bounds__(256,1) void k_expand(const float* agg, const uint32* w1pk,
        const uint32* w2pk, const float* b1, float* h2o, float* s2s, float* s2d){
    int tid = threadIdx.x;
    int hh = tid >> 5;
    uint32 w1r[64];
    #pragma unroll
    for (int q=0;q<16;q++){
        uvec4 u = *(const uvec4*)(w1pk + tid*64 + 4*q);
        w1r[4*q]=u.x; w1r[4*q+1]=u.y; w1r[4*q+2]=u.z; w1r[4*q+3]=u.w;
    }
    uint32 w2r[64];
    #pragma unroll
    for (int q=0;q<16;q++){
        uvec4 u = *(const uvec4*)(w2pk + tid*64 + 4*q);
        w2r[4*q]=u.x; w2r[4*q+1]=u.y; w2r[4*q+2]=u.z; w2r[4*q+3]=u.w;
    }
    float b1r[8];
    #pragma unroll
    for (int j=0;j<8;j++) b1r[j] = b1[8*tid+j];
    __shared__ float sred[256*17];    // stride 17: conflict-free scalar writes
    __shared__ float red2[64];
    for (int idx = blockIdx.x; idx < BB*NN; idx += gridDim.x){
        const float4* ap = (const float4*)(agg + (size_t)idx*128 + hh*16);
        float4 A0=ap[0], A1=ap[1], A2=ap[2], A3=ap[3];
        hf2 agh[7];
        agh[0]=__builtin_amdgcn_cvt_pkrtz(A0.x,A0.y);
        agh[1]=__builtin_amdgcn_cvt_pkrtz(A0.z,A0.w);
        agh[2]=__builtin_amdgcn_cvt_pkrtz(A1.x,A1.y);
        agh[3]=__builtin_amdgcn_cvt_pkrtz(A1.z,A1.w);
        agh[4]=__builtin_amdgcn_cvt_pkrtz(A2.x,A2.y);
        agh[5]=__builtin_amdgcn_cvt_pkrtz(A2.z,A2.w);
        agh[6]=__builtin_amdgcn_cvt_pkrtz(A3.x,A3.y);
        float v[8];
        #pragma unroll
        for (int j=0;j<8;j++){
            float s = b1r[j];
            #pragma unroll
            for (int kk=0;kk<7;kk++) s = FDOT2(agh[kk], u2h(w1r[j*8+kk]), s);
            v[j] = s > 0.f ? s : __expf(s) - 1.f;   // elu
        }
        hf2 vp[4];
        #pragma unroll
        for (int q=0;q<4;q++) vp[q] = __builtin_amdgcn_cvt_pkrtz(v[2*q], v[2*q+1]);
        #pragma unroll
        for (int j=0;j<16;j++){
            float s = 0.f;
            #pragma unroll
            for (int q=0;q<4;q++) s = FDOT2(vp[q], u2h(w2r[q*16+j]), s);
            sred[tid*17 + j] = s;
        }
        __syncthreads();
        int j = tid & 15, g = tid >> 4;
        float s = 0.f;
        #pragma unroll
        for (int i=0;i<16;i++) s += sred[(g + 16*i)*17 + j];
        s += __shfl_xor(s, 16);
        s += __shfl_xor(s, 32);
        int lane = tid & 63, w = tid >> 6;
        if (lane < 16) red2[w*16 + lane] = s;
        __syncthreads();
        if (tid < 15){
            float r = red2[tid] + red2[16+tid] + red2[32+tid] + red2[48+tid];
            if (tid < GO)      h2o[idx*GO + tid] = r;
            else if (tid==13)  s2s[idx] = r;
            else               s2d[idx] = r;
        }
        __syncthreads();
    }
}

// per-dst 1-head softmax + aggregation of h2 -> g (+bias2). Edge-parallel.
__global__ __launch_bounds__(64) void k_gat2agg(const float* h2, const float* s2src,
        const float* s2dst, const int* offs, const int* csr_src,
        const float* bias2, float* g){
    int lane = threadIdx.x;
    int blk = blockIdx.x;
    int b = blk & 7, n = blk >> 3;
    int bn = b*NN + n;
    int base = offs[n], deg = offs[n+1]-base;
    float sdd = s2dst[bn];
    float mloc = -1e30f;
    for (int i=lane;i<deg;i+=64){
        int s = csr_src[base+i];
        mloc = fmaxf(mloc, lrelu(s2src[b*NN+s] + sdd));
    }
    #pragma unroll
    for (int m=1;m<64;m<<=1) mloc = fmaxf(mloc, __shfl_xor(mloc,m));
    float dloc = 0.f;
    for (int i=lane;i<deg;i+=64){
        int s = csr_src[base+i];
        dloc += __expf(lrelu(s2src[b*NN+s] + sdd) - mloc);
    }
    #pragma unroll
    for (int m=1;m<64;m<<=1) dloc += __shfl_xor(dloc,m);
    float rd = 1.f / dloc;
    float acc[GO];
    #pragma unroll
    for (int c=0;c<GO;c++) acc[c]=0.f;
    for (int i=lane;i<deg;i+=64){
        int s = csr_src[base+i];
        float al = __expf(lrelu(s2src[b*NN+s] + sdd) - mloc) * rd;
        const float* hr = h2 + (size_t)(b*NN+s)*GO;
        #pragma unroll
        for (int c=0;c<GO;c++) acc[c] += al*hr[c];
    }
    #pragma unroll
    for (int c=0;c<GO;c++){
        #pragma unroll
        for (int m=1;m<64;m<<=1) acc[c] += __shfl_xor(acc[c],m);
    }
    if (lane==0){
        #pragma unroll
        for (int c=0;c<GO;c++) g[bn*GO+c] = acc[c] + bias2[c];
    }
}

// GRU step + fc_out; writes hn, xn, and d_out[b, t, n]
__global__ __launch_bounds__(256) void k_gru(int t, const float* feat, const float* gbuf,
        const float* Wih, const float* Whh, const float* bih, const float* bhh,
        const float* fcw, const float* fcb,
        float* hn, float* xn, float* out){
    __shared__ float sWih[192*27];
    __shared__ float sWhh[192*65];     // row stride 65: bank-conflict-free
    __shared__ float sb[449];          // bih[192], bhh[192], fcw[64], fcb
    __shared__ float gxs[4][28];
    __shared__ float hs[4][64];
    int tid = threadIdx.x;
    for (int i=tid;i<192*27;i+=256) sWih[i] = Wih[i];
    for (int i=tid;i<192*64;i+=256) sWhh[(i>>6)*65 + (i&63)] = Whh[i];
    for (int i=tid;i<192;i+=256){ sb[i] = bih[i]; sb[192+i] = bhh[i]; }
    if (tid<64) sb[384+tid] = fcw[tid];
    if (tid==0) sb[448] = fcb[0];
    __syncthreads();
    int w = tid>>6, lane = tid&63;
    for (int i=0;i<4;i++){
        int bn = blockIdx.x*16 + i*4 + w;
        int b = bn/NN, n = bn%NN;
        if (lane < GO)       gxs[w][lane] = gbuf[bn*GO+lane];
        else if (lane == GO) gxs[w][GO]   = xn[bn];
        else if (lane < 27)  gxs[w][lane] = feat[((size_t)(b*20 + 8 + t)*NN + n)*FEAT + (lane-14)];
        hs[w][lane] = hn[bn*HID + lane];
        __syncthreads();
        float ir = sb[lane], iz = sb[64+lane], inn = sb[128+lane];
        #pragma unroll
        for (int c=0;c<27;c++){
            float xv = gxs[w][c];
            ir  += sWih[lane*27        + c]*xv;
            iz  += sWih[(64+lane)*27   + c]*xv;
            inn += sWih[(128+lane)*27  + c]*xv;
        }
        float hr = sb[192+lane], hz = sb[256+lane], hnv = sb[320+lane];
        #pragma unroll
        for (int j=0;j<64;j++){
            float hv = hs[w][j];
            hr  += sWhh[lane*65        + j]*hv;
            hz  += sWhh[(64+lane)*65   + j]*hv;
            hnv += sWhh[(128+lane)*65  + j]*hv;
        }
        float r  = 1.f/(1.f+__expf(-(ir+hr)));
        float z  = 1.f/(1.f+__expf(-(iz+hz)));
        float nv = tanhf(inn + r*hnv);
        float hold = hs[w][lane];
        float hnew = (1.f - z)*nv + z*hold;
        hn[bn*HID+lane] = hnew;
        float xv = hnew * sb[384+lane];
        #pragma unroll
        for (int m=1;m<64;m<<=1) xv += __shfl_xor(xv,m);
        if (lane==0){
            float res = xv + sb[448];
            xn[bn] = res;
            out[(b*TPRED + t)*NN + n] = res;
        }
        __syncthreads();
    }
}

// ---------------- host ----------------

extern "C" void kernel_launch(void* const* d_in, const int* in_sizes, int n_in,
                              void* d_out, int out_size, void* d_ws, size_t ws_size,
                              hipStream_t stream){
    const float* pm25 = (const float*)d_in[0];
    const float* feat = (const float*)d_in[1];
    const int*   ei   = (const int*)  d_in[2];
    const float* W1   = (const float*)d_in[3];
    const float* a1s  = (const float*)d_in[4];
    const float* a1d  = (const float*)d_in[5];
    const float* b1   = (const float*)d_in[6];
    const float* W2   = (const float*)d_in[7];
    const float* a2s  = (const float*)d_in[8];
    const float* a2d  = (const float*)d_in[9];
    const float* b2   = (const float*)d_in[10];
    const float* Wih  = (const float*)d_in[11];
    const float* Whh  = (const float*)d_in[12];
    const float* bih  = (const float*)d_in[13];
    const float* bhh  = (const float*)d_in[14];
    const float* fcw  = (const float*)d_in[15];
    const float* fcb  = (const float*)d_in[16];
    float* out = (float*)d_out;

    float* f = (float*)d_ws;
    size_t o = 0;
    float* ssrc1 = f+o; o += (size_t)BB*NN*8;
    float* sdst1 = f+o; o += (size_t)BB*NN*8;
    float* agg   = f+o; o += (size_t)BB*NN*128;
    float* h2    = f+o; o += (size_t)BB*NN*GO + 8;
    float* s2s   = f+o; o += (size_t)BB*NN;
    float* s2d   = f+o; o += (size_t)BB*NN;
    float* gb    = f+o; o += (size_t)BB*NN*GO + 8;
    float* hn    = f+o; o += (size_t)BB*NN*HID;
    float* xn    = f+o; o += (size_t)BB*NN;
    float* Wsrc  = f+o; o += INDIM*8;
    float* Wdst  = f+o; o += INDIM*8;
    uint32* xpk  = (uint32*)(f+o); o += (size_t)BB*NN*8;
    uint32* w1pk = (uint32*)(f+o); o += (size_t)C1*8;      // 64KB f16 pairs
    uint32* w2pk = (uint32*)(f+o); o += (size_t)(C1/2)*16; // 64KB f16 pairs
    int* ibase  = (int*)(f+o);
    int* count  = ibase;
    int* cursor = ibase + NN;
    int* offs   = ibase + 2*NN;
    int* csr    = ibase + 2*NN + NN + 1;

    k_init   <<<2000,256,0,stream>>>(pm25, hn, xn, count);
    k_att1pre<<<112, 256,0,stream>>>(W1, a1s, a1d, Wsrc, Wdst);
    k_packW1 <<<64,  256,0,stream>>>(W1, w1pk);
    k_att2pre<<<4,   256,0,stream>>>(W2, a2s, a2d, w2pk);
    k_count  <<<67,  256,0,stream>>>(ei, count);
    k_scan   <<<1,  1024,0,stream>>>(count, offs, cursor);
    k_fill   <<<67,  256,0,stream>>>(ei, cursor, csr);

    for (int t=0; t<TPRED; t++){
        k_score  <<<32,  256,0,stream>>>(t, feat, xn, Wsrc, Wdst, ssrc1, sdst1, xpk);
        k_agg14  <<<8000, 64,0,stream>>>(xpk, ssrc1, sdst1, offs, csr, agg);
        k_expand <<<512, 256,0,stream>>>(agg, w1pk, w2pk, b1, h2, s2s, s2d);
        k_gat2agg<<<8000, 64,0,stream>>>(h2, s2s, s2d, offs, csr, b2, gb);
        k_gru    <<<500, 256,0,stream>>>(t, feat, gb, Wih, Whh, bih, bhh, fcw, fcb, hn, xn, out);
    }
}

// Round 7
// 940.514 us; speedup vs baseline: 4.0576x; 1.0501x over previous
//
#include <hip/hip_runtime.h>
#include <hip/hip_bf16.h>
#include <math.h>

#define BB 8
#define NN 1000
#define EE 16000
#define ETOT 17000   // E + N self loops
#define TPRED 12
#define FEAT 13
#define INDIM 14
#define HEADS 8
#define HG 256
#define C1 2048      // HEADS*HG
#define GO 13
#define HID 64

typedef unsigned int  uint32;
typedef unsigned short ushort16;
typedef uint32 uvec4 __attribute__((ext_vector_type(4)));
typedef __fp16 hf2 __attribute__((ext_vector_type(2)));

union U32H2 { uint32 u; hf2 h; };
__device__ __forceinline__ hf2 u2h(uint32 u){ U32H2 c; c.u=u; return c.h; }
__device__ __forceinline__ uint32 h2u(hf2 h){ U32H2 c; c.h=h; return c.u; }

#if __has_builtin(__builtin_amdgcn_fdot2)
__device__ __forceinline__ float FDOT2(hf2 a, hf2 b, float c){
    return __builtin_amdgcn_fdot2(a, b, c, false);
}
#else
__device__ __forceinline__ float FDOT2(hf2 a, hf2 b, float c){
    return c + (float)a.x*(float)b.x + (float)a.y*(float)b.y;
}
#endif

__device__ __forceinline__ float lrelu(float v){ return v > 0.f ? v : 0.2f*v; }

__device__ __forceinline__ ushort16 f2bf(float f){
    union { float f; uint32 u; } v; v.f = f;
    uint32 r = v.u + 0x7FFFu + ((v.u >> 16) & 1u);   // RNE
    return (ushort16)(r >> 16);
}
__device__ __forceinline__ uint32 pack2(float lo, float hi){
    return (uint32)f2bf(lo) | ((uint32)f2bf(hi) << 16);
}
__device__ __forceinline__ void cvt2(uint32 u, float& lo, float& hi){
    union { uint32 u; float f; } a, b;
    a.u = u << 16; b.u = u & 0xFFFF0000u;
    lo = a.f; hi = b.f;
}

// ---------------- setup kernels (once per launch) ----------------

// Wsrc[k][h] = sum_d W1[k, h*256+d] * a_src[h,d]   (and Wdst)
__global__ void k_att1pre(const float* W1, const float* asrc, const float* adst,
                          float* Wsrc, float* Wdst){
    int k = blockIdx.x >> 3, h = blockIdx.x & 7;
    int tid = threadIdx.x;                 // 256 threads = 256 dims
    float wv = W1[k*C1 + h*HG + tid];
    float ps = wv * asrc[h*HG + tid];
    float pd = wv * adst[h*HG + tid];
    #pragma unroll
    for (int m=1;m<64;m<<=1){ ps += __shfl_xor(ps,m); pd += __shfl_xor(pd,m); }
    __shared__ float rs[4], rd[4];
    int w = tid>>6;
    if ((tid&63)==0){ rs[w]=ps; rd[w]=pd; }
    __syncthreads();
    if (tid==0){
        Wsrc[k*8+h] = rs[0]+rs[1]+rs[2]+rs[3];
        Wdst[k*8+h] = rd[0]+rd[1]+rd[2]+rd[3];
    }
}

// pack W1 to f16 k-pairs: w1pk[c*8 + kk] = (W1[2kk][c], W1[2kk+1][c]), kk<7; slot 7 = 0
__global__ void k_packW1(const float* W1, uint32* w1pk){
    int i = blockIdx.x*blockDim.x + threadIdx.x;
    if (i < C1*8){
        int c = i >> 3, kk = i & 7;
        float lo = (kk < 7) ? W1[(2*kk)*C1 + c]   : 0.f;
        float hi = (kk < 7) ? W1[(2*kk+1)*C1 + c] : 0.f;
        w1pk[i] = h2u(__builtin_amdgcn_cvt_pkrtz(lo, hi));
    }
}

// per channel-PAIR m: 16-col matrix rows for channels 2m,2m+1
__global__ void k_att2pre(const float* W2, const float* a2s, const float* a2d,
                          uint32* w2pk){
    int m = blockIdx.x*blockDim.x + threadIdx.x;
    if (m < C1/2){
        int c0 = 2*m, c1 = 2*m+1;
        float colA[16], colB[16];
        float ssA=0.f, ddA=0.f, ssB=0.f, ddB=0.f;
        #pragma unroll
        for (int j=0;j<GO;j++){
            float wA = W2[c0*GO+j], wB = W2[c1*GO+j];
            colA[j]=wA; colB[j]=wB;
            ssA += wA*a2s[j]; ddA += wA*a2d[j];
            ssB += wB*a2s[j]; ddB += wB*a2d[j];
        }
        colA[13]=ssA; colA[14]=ddA; colA[15]=0.f;
        colB[13]=ssB; colB[14]=ddB; colB[15]=0.f;
        #pragma unroll
        for (int j=0;j<16;j++)
            w2pk[m*16+j] = h2u(__builtin_amdgcn_cvt_pkrtz(colA[j], colB[j]));
    }
}

// init hn/xn/count AND compute step-0 scores + packed x (needs Wsrc/Wdst ready)
__global__ void k_init(const float* pm25, const float* feat,
                       const float* Wsrc, const float* Wdst,
                       float* hn, float* xn, int* count,
                       float* ssrc, float* sdst, uint32* xpk){
    int i = blockIdx.x*blockDim.x + threadIdx.x;
    if (i < BB*NN*HID) hn[i] = 0.f;
    if (i < NN) count[i] = 0;
    if (i < BB*NN){
        int b = i/NN, n = i%NN;
        float x[INDIM];
        x[0] = pm25[(b*8 + 7)*NN + n];
        xn[i] = x[0];
        const float* fp = feat + ((size_t)(b*20 + 8)*NN + n)*FEAT;
        #pragma unroll
        for (int k=0;k<FEAT;k++) x[k+1] = fp[k];
        #pragma unroll
        for (int h=0;h<8;h++){
            float ss=0.f, dd=0.f;
            #pragma unroll
            for (int k=0;k<INDIM;k++){ ss += x[k]*Wsrc[k*8+h]; dd += x[k]*Wdst[k*8+h]; }
            ssrc[i*8+h] = ss; sdst[i*8+h] = dd;
        }
        #pragma unroll
        for (int p=0;p<7;p++) xpk[i*8+p] = pack2(x[2*p], x[2*p+1]);
        xpk[i*8+7] = 0u;
    }
}

__global__ void k_count(const int* ei, int* count){
    int e = blockIdx.x*blockDim.x + threadIdx.x;
    if (e < ETOT){
        int dst = (e<EE) ? ei[EE+e] : (e-EE);
        atomicAdd(&count[dst], 1);
    }
}

__global__ void k_scan(const int* count, int* offs, int* cursor){
    __shared__ int s[1024];
    int tid = threadIdx.x;
    int myc = (tid<NN) ? count[tid] : 0;
    s[tid] = myc;
    __syncthreads();
    for (int d=1; d<1024; d<<=1){
        int v = (tid>=d) ? s[tid-d] : 0;
        __syncthreads();
        s[tid] += v;
        __syncthreads();
    }
    if (tid<NN){
        int off = s[tid] - myc;   // exclusive
        offs[tid] = off; cursor[tid] = off;
    }
    if (tid==NN-1) offs[NN] = s[tid];
}

__global__ void k_fill(const int* ei, int* cursor, int* csr_src){
    int e = blockIdx.x*blockDim.x + threadIdx.x;
    if (e < ETOT){
        int src = (e<EE) ? ei[e]    : (e-EE);
        int dst = (e<EE) ? ei[EE+e] : (e-EE);
        int pos = atomicAdd(&cursor[dst], 1);
        csr_src[pos] = src;
    }
}

// ---------------- per-step kernels ----------------

// per (b,dst), 1 wave: 8-head softmax over incoming edges, aggregate 14-dim x:
// agg[bn*128 + h*16 + k] = sum_src alpha_h * x[src][k]
__global__ __launch_bounds__(64) void k_agg14(const uint32* xpk, const float* ssrc,
        const float* sdst, const int* offs, const int* csr, float* agg){
    int lane = threadIdx.x;
    int blk = blockIdx.x;
    int b = blk & 7, dstn = blk >> 3;
    int bn = b*NN + dstn;
    int base = offs[dstn], deg = offs[dstn+1]-base;
    int h = lane & 7, slot = lane >> 3;
    float sdd = sdst[bn*8 + h];
    // pass 1: per-head max
    float mloc = -1e30f;
    for (int i=slot;i<deg;i+=8){
        int s = csr[base+i];
        mloc = fmaxf(mloc, lrelu(ssrc[(b*NN+s)*8+h]+sdd));
    }
    mloc = fmaxf(mloc, __shfl_xor(mloc,8));
    mloc = fmaxf(mloc, __shfl_xor(mloc,16));
    mloc = fmaxf(mloc, __shfl_xor(mloc,32));
    // pass 2: per-head denom
    float dloc = 0.f;
    for (int i=slot;i<deg;i+=8){
        int s = csr[base+i];
        dloc += __expf(lrelu(ssrc[(b*NN+s)*8+h]+sdd)-mloc);
    }
    dloc += __shfl_xor(dloc,8); dloc += __shfl_xor(dloc,16); dloc += __shfl_xor(dloc,32);
    float rden = 1.f/dloc;
    // pass 3 remap: lane = h2*8 + kk, kk owns channels 2kk,2kk+1
    int kk = lane & 7, h2 = lane >> 3;
    float m2   = __shfl(mloc, h2);
    float r2   = __shfl(rden, h2);
    float sdd2 = __shfl(sdd,  h2);
    float a0=0.f, a1=0.f;
    for (int e=0;e<deg;e++){
        int s = csr[base+e];
        float sc = lrelu(ssrc[(b*NN+s)*8+h2] + sdd2);
        float al = __expf(sc - m2)*r2;
        float x0,x1; cvt2(xpk[(b*NN+s)*8+kk], x0, x1);
        a0 += al*x0; a1 += al*x1;
    }
    float2 st; st.x = a0; st.y = a1;
    *(float2*)(agg + (size_t)bn*128 + h2*16 + 2*kk) = st;
}

// fused expand(14->2048) + bias + elu + contract(2048->16)
__global__ __launch_bounds__(256,1) void k_expand(const float* agg, const uint32* w1pk,
        const uint32* w2pk, const float* b1, float* h2o, float* s2s, float* s2d){
    int tid = threadIdx.x;
    int hh = tid >> 5;
    uint32 w1r[64];
    #pragma unroll
    for (int q=0;q<16;q++){
        uvec4 u = *(const uvec4*)(w1pk + tid*64 + 4*q);
        w1r[4*q]=u.x; w1r[4*q+1]=u.y; w1r[4*q+2]=u.z; w1r[4*q+3]=u.w;
    }
    uint32 w2r[64];
    #pragma unroll
    for (int q=0;q<16;q++){
        uvec4 u = *(const uvec4*)(w2pk + tid*64 + 4*q);
        w2r[4*q]=u.x; w2r[4*q+1]=u.y; w2r[4*q+2]=u.z; w2r[4*q+3]=u.w;
    }
    float b1r[8];
    #pragma unroll
    for (int j=0;j<8;j++) b1r[j] = b1[8*tid+j];
    __shared__ float sred[256*17];    // stride 17: conflict-free scalar writes
    __shared__ float red2[64];
    for (int idx = blockIdx.x; idx < BB*NN; idx += gridDim.x){
        const float4* ap = (const float4*)(agg + (size_t)idx*128 + hh*16);
        float4 A0=ap[0], A1=ap[1], A2=ap[2], A3=ap[3];
        hf2 agh[7];
        agh[0]=__builtin_amdgcn_cvt_pkrtz(A0.x,A0.y);
        agh[1]=__builtin_amdgcn_cvt_pkrtz(A0.z,A0.w);
        agh[2]=__builtin_amdgcn_cvt_pkrtz(A1.x,A1.y);
        agh[3]=__builtin_amdgcn_cvt_pkrtz(A1.z,A1.w);
        agh[4]=__builtin_amdgcn_cvt_pkrtz(A2.x,A2.y);
        agh[5]=__builtin_amdgcn_cvt_pkrtz(A2.z,A2.w);
        agh[6]=__builtin_amdgcn_cvt_pkrtz(A3.x,A3.y);
        float v[8];
        #pragma unroll
        for (int j=0;j<8;j++){
            float s = b1r[j];
            #pragma unroll
            for (int kk=0;kk<7;kk++) s = FDOT2(agh[kk], u2h(w1r[j*8+kk]), s);
            v[j] = s > 0.f ? s : __expf(s) - 1.f;   // elu
        }
        hf2 vp[4];
        #pragma unroll
        for (int q=0;q<4;q++) vp[q] = __builtin_amdgcn_cvt_pkrtz(v[2*q], v[2*q+1]);
        #pragma unroll
        for (int j=0;j<16;j++){
            float s = 0.f;
            #pragma unroll
            for (int q=0;q<4;q++) s = FDOT2(vp[q], u2h(w2r[q*16+j]), s);
            sred[tid*17 + j] = s;
        }
        __syncthreads();
        int j = tid & 15, g = tid >> 4;
        float s = 0.f;
        #pragma unroll
        for (int i=0;i<16;i++) s += sred[(g + 16*i)*17 + j];
        s += __shfl_xor(s, 16);
        s += __shfl_xor(s, 32);
        int lane = tid & 63, w = tid >> 6;
        if (lane < 16) red2[w*16 + lane] = s;
        __syncthreads();
        if (tid < 15){
            float r = red2[tid] + red2[16+tid] + red2[32+tid] + red2[48+tid];
            if (tid < GO)      h2o[idx*GO + tid] = r;
            else if (tid==13)  s2s[idx] = r;
            else               s2d[idx] = r;
        }
        __syncthreads();
    }
}

// fused: gat2agg (per-bn softmax+aggregate, wave-parallel) -> GRU -> fc_out
// -> next-step score/xpk. One wave per bn, 4 waves/block, 4 bn-rounds.
__global__ __launch_bounds__(256) void k_tail(int t, int last,
        const float* feat, const int* offs, const int* csr,
        const float* h2, const float* s2src, const float* s2dst, const float* b2,
        const float* Wih, const float* Whh, const float* bih, const float* bhh,
        const float* fcw, const float* fcb, const float* Wsrc, const float* Wdst,
        float* hn, float* xn, float* out,
        float* ssrc, float* sdst, uint32* xpk){
    __shared__ float sWih[192*27];
    __shared__ float sWhh[192*65];     // row stride 65: bank-conflict-free
    __shared__ float sb[449];          // bih[192], bhh[192], fcw[64], fcb
    __shared__ float sWa[224];         // Wsrc[112], Wdst[112]
    __shared__ float gxs[4][28];
    __shared__ float hs[4][64];
    int tid = threadIdx.x;
    for (int i=tid;i<192*27;i+=256) sWih[i] = Wih[i];
    for (int i=tid;i<192*64;i+=256) sWhh[(i>>6)*65 + (i&63)] = Whh[i];
    for (int i=tid;i<192;i+=256){ sb[i] = bih[i]; sb[192+i] = bhh[i]; }
    if (tid<64) sb[384+tid] = fcw[tid];
    if (tid==0) sb[448] = fcb[0];
    if (tid<112){ sWa[tid] = Wsrc[tid]; sWa[112+tid] = Wdst[tid]; }
    __syncthreads();
    int w = tid>>6, lane = tid&63;
    for (int i=0;i<4;i++){
        int bn = blockIdx.x*16 + i*4 + w;
        int b = bn/NN, n = bn%NN;
        // ---- GAT2 aggregation (results broadcast to all lanes via butterfly) ----
        int base = offs[n], deg = offs[n+1]-base;
        float sdd = s2dst[bn];
        float mloc = -1e30f;
        for (int e=lane;e<deg;e+=64){
            int s = csr[base+e];
            mloc = fmaxf(mloc, lrelu(s2src[b*NN+s] + sdd));
        }
        #pragma unroll
        for (int m=1;m<64;m<<=1) mloc = fmaxf(mloc, __shfl_xor(mloc,m));
        float dloc = 0.f;
        for (int e=lane;e<deg;e+=64){
            int s = csr[base+e];
            dloc += __expf(lrelu(s2src[b*NN+s] + sdd) - mloc);
        }
        #pragma unroll
        for (int m=1;m<64;m<<=1) dloc += __shfl_xor(dloc,m);
        float rdv = 1.f / dloc;
        float acc[GO];
        #pragma unroll
        for (int c=0;c<GO;c++) acc[c]=0.f;
        for (int e=lane;e<deg;e+=64){
            int s = csr[base+e];
            float al = __expf(lrelu(s2src[b*NN+s] + sdd) - mloc) * rdv;
            const float* hr = h2 + (size_t)(b*NN+s)*GO;
            #pragma unroll
            for (int c=0;c<GO;c++) acc[c] += al*hr[c];
        }
        #pragma unroll
        for (int c=0;c<GO;c++){
            #pragma unroll
            for (int m=1;m<64;m<<=1) acc[c] += __shfl_xor(acc[c],m);
        }
        if (lane==0){
            #pragma unroll
            for (int c=0;c<GO;c++) gxs[w][c] = acc[c] + b2[c];
            gxs[w][GO] = xn[bn];
        }
        if (lane>=14 && lane<27)
            gxs[w][lane] = feat[((size_t)(b*20 + 8 + t)*NN + n)*FEAT + (lane-14)];
        hs[w][lane] = hn[bn*HID + lane];
        __syncthreads();
        // ---- GRU ----
        float ir = sb[lane], iz = sb[64+lane], inn = sb[128+lane];
        #pragma unroll
        for (int c=0;c<27;c++){
            float xv = gxs[w][c];
            ir  += sWih[lane*27        + c]*xv;
            iz  += sWih[(64+lane)*27   + c]*xv;
            inn += sWih[(128+lane)*27  + c]*xv;
        }
        float hr = sb[192+lane], hz = sb[256+lane], hnv = sb[320+lane];
        #pragma unroll
        for (int j=0;j<64;j++){
            float hv = hs[w][j];
            hr  += sWhh[lane*65        + j]*hv;
            hz  += sWhh[(64+lane)*65   + j]*hv;
            hnv += sWhh[(128+lane)*65  + j]*hv;
        }
        float r  = 1.f/(1.f+__expf(-(ir+hr)));
        float z  = 1.f/(1.f+__expf(-(iz+hz)));
        float nv = tanhf(inn + r*hnv);
        float hold = hs[w][lane];
        float hnew = (1.f - z)*nv + z*hold;
        hn[bn*HID+lane] = hnew;
        float xv = hnew * sb[384+lane];
        #pragma unroll
        for (int m=1;m<64;m<<=1) xv += __shfl_xor(xv,m);
        float res = xv + sb[448];    // all lanes have it
        if (lane==0){
            xn[bn] = res;
            out[(b*TPRED + t)*NN + n] = res;
        }
        // ---- score + pack for step t+1 ----
        if (!last){
            const float* fp = feat + ((size_t)(b*20 + 9 + t)*NN + n)*FEAT;
            if (lane < 16){
                int h = lane & 7;
                const float* Wa = (lane<8) ? sWa : sWa+112;
                float s = res * Wa[h];
                #pragma unroll
                for (int k=1;k<14;k++) s += fp[k-1]*Wa[k*8+h];
                if (lane<8) ssrc[bn*8+h] = s; else sdst[bn*8+h] = s;
            } else if (lane < 23){
                int p = lane - 16;
                float lo = (p==0) ? res : fp[2*p-1];
                float hi = fp[2*p];
                xpk[bn*8+p] = pack2(lo, hi);
            } else if (lane == 23){
                xpk[bn*8+7] = 0u;
            }
        }
        __syncthreads();
    }
}

// ---------------- host ----------------

extern "C" void kernel_launch(void* const* d_in, const int* in_sizes, int n_in,
                              void* d_out, int out_size, void* d_ws, size_t ws_size,
                              hipStream_t stream){
    const float* pm25 = (const float*)d_in[0];
    const float* feat = (const float*)d_in[1];
    const int*   ei   = (const int*)  d_in[2];
    const float* W1   = (const float*)d_in[3];
    const float* a1s  = (const float*)d_in[4];
    const float* a1d  = (const float*)d_in[5];
    const float* b1   = (const float*)d_in[6];
    const float* W2   = (const float*)d_in[7];
    const float* a2s  = (const float*)d_in[8];
    const float* a2d  = (const float*)d_in[9];
    const float* b2   = (const float*)d_in[10];
    const float* Wih  = (const float*)d_in[11];
    const float* Whh  = (const float*)d_in[12];
    const float* bih  = (const float*)d_in[13];
    const float* bhh  = (const float*)d_in[14];
    const float* fcw  = (const float*)d_in[15];
    const float* fcb  = (const float*)d_in[16];
    float* out = (float*)d_out;

    float* f = (float*)d_ws;
    size_t o = 0;
    float* ssrc1 = f+o; o += (size_t)BB*NN*8;
    float* sdst1 = f+o; o += (size_t)BB*NN*8;
    float* agg   = f+o; o += (size_t)BB*NN*128;
    float* h2    = f+o; o += (size_t)BB*NN*GO + 8;
    float* s2s   = f+o; o += (size_t)BB*NN;
    float* s2d   = f+o; o += (size_t)BB*NN;
    float* hn    = f+o; o += (size_t)BB*NN*HID;
    float* xn    = f+o; o += (size_t)BB*NN;
    float* Wsrc  = f+o; o += INDIM*8;
    float* Wdst  = f+o; o += INDIM*8;
    uint32* xpk  = (uint32*)(f+o); o += (size_t)BB*NN*8;
    uint32* w1pk = (uint32*)(f+o); o += (size_t)C1*8;      // 64KB f16 pairs
    uint32* w2pk = (uint32*)(f+o); o += (size_t)(C1/2)*16; // 64KB f16 pairs
    int* ibase  = (int*)(f+o);
    int* count  = ibase;
    int* cursor = ibase + NN;
    int* offs   = ibase + 2*NN;
    int* csr    = ibase + 2*NN + NN + 1;

    k_att1pre<<<112, 256,0,stream>>>(W1, a1s, a1d, Wsrc, Wdst);
    k_packW1 <<<64,  256,0,stream>>>(W1, w1pk);
    k_att2pre<<<4,   256,0,stream>>>(W2, a2s, a2d, w2pk);
    k_init   <<<2000,256,0,stream>>>(pm25, feat, Wsrc, Wdst, hn, xn, count,
                                     ssrc1, sdst1, xpk);
    k_count  <<<67,  256,0,stream>>>(ei, count);
    k_scan   <<<1,  1024,0,stream>>>(count, offs, cursor);
    k_fill   <<<67,  256,0,stream>>>(ei, cursor, csr);

    for (int t=0; t<TPRED; t++){
        k_agg14  <<<8000, 64,0,stream>>>(xpk, ssrc1, sdst1, offs, csr, agg);
        k_expand <<<512, 256,0,stream>>>(agg, w1pk, w2pk, b1, h2, s2s, s2d);
        k_tail   <<<500, 256,0,stream>>>(t, (t==TPRED-1)?1:0, feat, offs, csr,
                                         h2, s2s, s2d, b2,
                                         Wih, Whh, bih, bhh, fcw, fcb, Wsrc, Wdst,
                                         hn, xn, out, ssrc1, sdst1, xpk);
    }
}